// Round 8
// baseline (169.609 us; speedup 1.0000x reference)
//
#include <hip/hip_runtime.h>

typedef __attribute__((ext_vector_type(8))) short bf16x8;
typedef __attribute__((ext_vector_type(4))) float f32x4;
typedef unsigned short ushort_t;
typedef unsigned int uint_t;

constexpr int PEP = 15;   // peptide length
constexpr int D   = 64;   // feature dim
constexpr int L   = 34;   // mhc length (stage-1 contraction)
constexpr int OC  = 128;  // output channels
constexpr int KS  = 9;    // kernel size
constexpr int TO  = 7;    // output positions
constexpr int OK  = OC * KS;      // 1152 stage-1 rows
constexpr int MTG = OK / 16;      // 72 global M-tiles
constexpr int NCH = 8;            // o-chunks total per n
constexpr int NCHB = 4;           // chunks per block (grid-split 2x)
constexpr int CHO = OC / NCH;     // 16 o per chunk
constexpr int MT_CH = (CHO * KS) / 16;  // 9 M-tiles per chunk
constexpr int CTS = 145;          // C^T row stride (odd -> stage-2 reads 2/bank free)
constexpr int SOS = CHO * TO;     // 112 (%32=16 -> writer lanes {15,31,47,63} 2-way free)
constexpr int WPN = 2 * MTG * 2 * 64 * 8;  // 147456 ushorts in Wprep
// smem: CT f32 [64][145] bytes [0,37120) (aliases one-time mT staging, 16384 B)
//       so f32 [4][112]  bytes [37120, 38912)
constexpr int SMEM_BYTES = 64 * CTS * 4 + 4 * SOS * 4;  // 38912

__device__ __forceinline__ ushort_t f2bf(float v) {
    uint_t u = __float_as_uint(v);
    return (ushort_t)((u + 0x7fffu + ((u >> 16) & 1u)) >> 16);   // RTNE
}
__device__ __forceinline__ float bf2f(ushort_t h) {
    return __uint_as_float(((uint_t)h) << 16);
}

// DPP row_shr:N accumulate (pure VALU — no LDS-pipe traffic, unlike __shfl_xor
// which lowers to ds_bpermute). bound_ctrl=true zero-fills lanes < N in row.
template <int CTRL>
__device__ __forceinline__ float dpp_shr_add(float v) {
    int x = __builtin_amdgcn_update_dpp(0, __float_as_int(v), CTRL, 0xF, 0xF, true);
    return v + __int_as_float(x);
}

// Pre-kernel: W[ok][l] f32 -> fragment-ready hi/lo bf16 (unchanged layout).
// ushort index: sp*73728 + mt*1024 + ks*512 + lane*8 + i
//   row ok = mt*16 + (lane&15);  k-col l = (lane>>4)*8 + i + 32*ks  (0 if l>=34)
__global__ void wprep_kernel(const float* __restrict__ W, ushort_t* __restrict__ wp) {
    int x = blockIdx.x * 256 + threadIdx.x;
    if (x >= WPN) return;
    int i  = x & 7;
    int ln = (x >> 3) & 63;
    int ks = (x >> 9) & 1;
    int mt = (x >> 10) % MTG;
    int sp = x / (MTG * 1024);
    int ok = mt * 16 + (ln & 15);
    int l  = (ln >> 4) * 8 + i + 32 * ks;
    float v = (l < L) ? W[ok * L + l] : 0.0f;
    ushort_t hi = f2bf(v);
    if (sp == 0) wp[x] = hi;
    else         wp[x] = f2bf(v - bf2f(hi));
}

// Grid (bs, 2): block = (n, half). Each block: 4 chunks of 16 o-channels.
// Per chunk: stage-1 MFMA -> CT; BAR1; stage-2 VALU + DPP row-reduce -> so
// (4 partials); BAR2; epilogue. The 9th M-tile rotates across waves by chunk.
// launch_bounds (256,3): cap ~170 regs — round-7's (256,4) capped the unified
// VGPR+AGPR file at 128 and spilled (WRITE_SIZE 7.2->19.7 MB). Occupancy is
// ~12 waves/CU either way, so (256,3) strictly dominates.
__global__ __launch_bounds__(256, 3) void iconv_mfma(
    const float* __restrict__ pep,
    const float* __restrict__ mhc,
    const ushort_t* __restrict__ wp,
    const float* __restrict__ bias,
    float* __restrict__ out)
{
    __shared__ __align__(16) char smem[SMEM_BYTES];
    const int n    = blockIdx.x;
    const int c0   = blockIdx.y * NCHB;             // chunk offset for this block
    const int tid  = threadIdx.x;
    const int lane = tid & 63;
    const int w    = tid >> 6;

    // peptide column (lane = d), kept in registers through both stages
    float p[PEP];
    {
        const float* pp = pep + (size_t)n * PEP * D + lane;
        #pragma unroll
        for (int j = 0; j < PEP; ++j) p[j] = pp[j * D];
    }

    // Stage m^T into LDS as hi/lo bf16, XOR-swizzled (one-time)
    {
        const float* mp = mhc + (size_t)n * L * D + lane;
        #pragma unroll
        for (int j = 0; j < 16; ++j) {
            int l = w + 4 * j;
            float v = (l < L) ? mp[l * D] : 0.0f;
            ushort_t hi = f2bf(v);
            ushort_t lo = f2bf(v - bf2f(hi));
            int byte = (lane * 128 + l * 2) ^ ((lane & 7) << 4);
            *(ushort_t*)(smem + byte)        = hi;
            *(ushort_t*)(smem + 8192 + byte) = lo;
        }
    }
    __syncthreads();

    // B-fragments (m), persistent in registers: [nt][ks][hi/lo]
    bf16x8 bf[4][2][2];
    #pragma unroll
    for (int nt = 0; nt < 4; ++nt) {
        int d = (lane & 15) + 16 * nt;
        #pragma unroll
        for (int ks = 0; ks < 2; ++ks) {
            int l0 = (lane >> 4) * 8 + 32 * ks;
            int byte = (d * 128 + l0 * 2) ^ ((d & 7) << 4);
            bf[nt][ks][0] = *(const bf16x8*)(smem + byte);
            bf[nt][ks][1] = *(const bf16x8*)(smem + 8192 + byte);
        }
    }
    __syncthreads();   // mT dead; CT may overwrite

    float* CT  = (float*)smem;                      // [d][CTS]
    float* so  = (float*)(smem + 64 * CTS * 4);     // [4][SOS]
    float* CTl = CT + lane * CTS;                   // stage-2 row base

    // one M-tile of stage 1: load W-frags, 6 MFMAs (hi/lo 3-product), relu->CT
    auto do_tile = [&](int cg, int mtl) {
        const ushort_t* base = wp + (size_t)(cg * MT_CH + mtl) * 1024 + lane * 8;
        bf16x8 ah0 = *(const bf16x8*)(base);
        bf16x8 ah1 = *(const bf16x8*)(base + 512);
        bf16x8 al0 = *(const bf16x8*)(base + MTG * 1024);
        bf16x8 al1 = *(const bf16x8*)(base + MTG * 1024 + 512);

        f32x4 acc[4];
        #pragma unroll
        for (int nt = 0; nt < 4; ++nt) acc[nt] = (f32x4){0.f, 0.f, 0.f, 0.f};
        #pragma unroll
        for (int nt = 0; nt < 4; ++nt) {
            acc[nt] = __builtin_amdgcn_mfma_f32_16x16x32_bf16(ah0, bf[nt][0][0], acc[nt], 0, 0, 0);
            acc[nt] = __builtin_amdgcn_mfma_f32_16x16x32_bf16(ah1, bf[nt][1][0], acc[nt], 0, 0, 0);
            acc[nt] = __builtin_amdgcn_mfma_f32_16x16x32_bf16(ah0, bf[nt][0][1], acc[nt], 0, 0, 0);
            acc[nt] = __builtin_amdgcn_mfma_f32_16x16x32_bf16(ah1, bf[nt][1][1], acc[nt], 0, 0, 0);
            acc[nt] = __builtin_amdgcn_mfma_f32_16x16x32_bf16(al0, bf[nt][0][0], acc[nt], 0, 0, 0);
            acc[nt] = __builtin_amdgcn_mfma_f32_16x16x32_bf16(al1, bf[nt][1][0], acc[nt], 0, 0, 0);
        }

        int r0 = mtl * 16 + (lane >> 4) * 4;
        #pragma unroll
        for (int nt = 0; nt < 4; ++nt) {
            int d = (lane & 15) + 16 * nt;
            float* dst = CT + d * CTS + r0;
            dst[0] = fmaxf(acc[nt][0], 0.f);
            dst[1] = fmaxf(acc[nt][1], 0.f);
            dst[2] = fmaxf(acc[nt][2], 0.f);
            dst[3] = fmaxf(acc[nt][3], 0.f);
        }
    };

    for (int c = 0; c < NCHB; ++c) {
        const int cg = c0 + c;                      // global chunk id

        // ---------- stage 1: tiles {w, w+4} + rotated 9th tile ----------
        do_tile(cg, w);
        do_tile(cg, w + 4);
        if (w == (cg & 3)) do_tile(cg, 8);          // balanced across chunks
        __syncthreads();   // BAR1: CT complete

        // ---------- stage 2: f32 VALU, lane = d; two oi-halves to cut
        // concurrently-live registers (same op count & numerics) ----------
        #pragma unroll
        for (int h = 0; h < 2; ++h) {
            float a2[2][TO];
            #pragma unroll
            for (int oi = 0; oi < 2; ++oi)
                #pragma unroll
                for (int t = 0; t < TO; ++t) a2[oi][t] = 0.f;

            #pragma unroll
            for (int oi = 0; oi < 2; ++oi) {
                const float* row = CTl + (w * 4 + h * 2 + oi) * KS;  // conflict-free
                #pragma unroll
                for (int k = 0; k < KS; ++k) {
                    float kk = row[k];
                    #pragma unroll
                    for (int t = 0; t < TO; ++t) a2[oi][t] = fmaf(kk, p[t + k], a2[oi][t]);
                }
            }

            // DPP row-reduce over 16-lane groups (VALU only); group sum in
            // lane 15 of each row16; 4 partials -> so.
            #pragma unroll
            for (int oi = 0; oi < 2; ++oi) {
                #pragma unroll
                for (int t = 0; t < TO; ++t) {
                    float a = a2[oi][t];
                    a = dpp_shr_add<0x111>(a);   // row_shr:1
                    a = dpp_shr_add<0x112>(a);   // row_shr:2
                    a = dpp_shr_add<0x114>(a);   // row_shr:4
                    a = dpp_shr_add<0x118>(a);   // row_shr:8
                    if ((lane & 15) == 15)
                        so[(lane >> 4) * SOS + (w * 4 + h * 2 + oi) * TO + t] = a;
                }
            }
        }
        __syncthreads();   // BAR2: so complete; CT reads complete

        // epilogue: this chunk's 112 outputs (contiguous in out)
        if (tid < SOS) {
            int o = cg * CHO + tid / TO;
            float v = (so[tid] + so[SOS + tid]) +
                      (so[2 * SOS + tid] + so[3 * SOS + tid]);
            out[(size_t)n * OC * TO + cg * SOS + tid] = v + bias[o];
        }
        // no barrier: next stage-1 writes CT only (so disjoint); next so-write
        // is after next BAR1 which orders it against these so-reads.
    }
}

// ---------------- fallback (f32 VALU, known-good) ----------------
__global__ __launch_bounds__(256, 4) void iconv_f32(
    const float* __restrict__ pep, const float* __restrict__ mhc,
    const float* __restrict__ wsrc, const float* __restrict__ bias,
    float* __restrict__ out)
{
    __shared__ float so[4 * 900];
    const int n = blockIdx.x, tid = threadIdx.x, lane = tid & 63;
    const int w = __builtin_amdgcn_readfirstlane(tid >> 6);
    float m[L];
    { const float* mp = mhc + (size_t)n * L * D + lane;
      #pragma unroll
      for (int l = 0; l < L; ++l) m[l] = mp[l * D]; }
    float p[PEP];
    { const float* pp = pep + (size_t)n * PEP * D + lane;
      #pragma unroll
      for (int j = 0; j < PEP; ++j) p[j] = pp[j * D]; }
    for (int oo = 0; oo < OC / 4; ++oo) {
        const int o = w * (OC / 4) + oo;
        float acc[TO];
        #pragma unroll
        for (int t = 0; t < TO; ++t) acc[t] = 0.f;
        #pragma unroll
        for (int k = 0; k < KS; ++k) {
            const float2* wrow = reinterpret_cast<const float2*>(wsrc + (size_t)o * KS * L);
            float wr[L];
            #pragma unroll
            for (int q = 0; q < L / 2; ++q) {
                float2 v = wrow[k * (L / 2) + q];
                wr[q * 2] = v.x; wr[q * 2 + 1] = v.y;
            }
            float k0 = 0.f, k1 = 0.f, k2 = 0.f, k3 = 0.f;
            #pragma unroll
            for (int l = 0; l < 32; l += 4) {
                k0 = fmaf(m[l], wr[l], k0);   k1 = fmaf(m[l + 1], wr[l + 1], k1);
                k2 = fmaf(m[l + 2], wr[l + 2], k2); k3 = fmaf(m[l + 3], wr[l + 3], k3);
            }
            k0 = fmaf(m[32], wr[32], k0); k1 = fmaf(m[33], wr[33], k1);
            float kk = fmaxf((k0 + k2) + (k1 + k3), 0.f);
            #pragma unroll
            for (int t = 0; t < TO; ++t) acc[t] = fmaf(p[t + k], kk, acc[t]);
        }
        #pragma unroll
        for (int t = 0; t < TO; ++t) {
            float a = acc[t];
            a += __shfl_xor(a, 1, 64); a += __shfl_xor(a, 2, 64);
            a += __shfl_xor(a, 4, 64); a += __shfl_xor(a, 8, 64);
            if ((lane & 15) == 0) so[(lane >> 4) * 900 + o * TO + t] = a;
        }
    }
    __syncthreads();
    float* on = out + (size_t)n * OC * TO;
    for (int i = tid; i < OC * TO; i += 256) {
        int o = i / TO;
        on[i] = (so[i] + so[900 + i]) + (so[1800 + i] + so[2700 + i]) + bias[o];
    }
}

extern "C" void kernel_launch(void* const* d_in, const int* in_sizes, int n_in,
                              void* d_out, int out_size, void* d_ws, size_t ws_size,
                              hipStream_t stream) {
    const float* pep  = (const float*)d_in[0];
    const float* mhc  = (const float*)d_in[1];
    const float* W    = (const float*)d_in[2];
    const float* bias = (const float*)d_in[3];
    float* out        = (float*)d_out;
    const int bs = in_sizes[0] / (PEP * D);

    const size_t need = (size_t)WPN * sizeof(ushort_t);   // 294912 B
    if (d_ws != nullptr && ws_size >= need) {
        ushort_t* wpx = (ushort_t*)d_ws;
        wprep_kernel<<<(WPN + 255) / 256, 256, 0, stream>>>(W, wpx);
        iconv_mfma<<<dim3(bs, 2), 256, 0, stream>>>(pep, mhc, wpx, bias, out);
    } else {
        iconv_f32<<<bs, 256, 0, stream>>>(pep, mhc, W, bias, out);
    }
}

// Round 10
// 150.258 us; speedup vs baseline: 1.1288x; 1.1288x over previous
//
#include <hip/hip_runtime.h>

typedef __attribute__((ext_vector_type(8))) short bf16x8;
typedef __attribute__((ext_vector_type(4))) float f32x4;
typedef unsigned short ushort_t;
typedef unsigned int uint_t;

constexpr int PEP = 15;   // peptide length
constexpr int D   = 64;   // feature dim
constexpr int L   = 34;   // mhc length (stage-1 contraction)
constexpr int OC  = 128;  // output channels
constexpr int KS  = 9;    // kernel size
constexpr int TO  = 7;    // output positions
constexpr int OK  = OC * KS;      // 1152 stage-1 rows
constexpr int MTG = OK / 16;      // 72 global M-tiles
constexpr int NCH = 8;            // o-chunks total per n
constexpr int NCHB = 4;           // chunks per block (grid-split 2x)
constexpr int CHO = OC / NCH;     // 16 o per chunk
constexpr int MT_CH = (CHO * KS) / 16;  // 9 M-tiles per chunk
constexpr int CTS = 145;          // C^T row stride (odd -> stage-2 reads 2/bank free)
constexpr int SOS = CHO * TO;     // 112
// Wprep layout (294912 B total):
//   [0, 36864)        ushort: hi frags, k=0..31:  mt*512 + lane*8 + i
//   [36864, 73728)    ushort: lo frags, same indexing
//   f32 tail at ushort-offset 73728 (byte 147456), 36864 floats:
//       mt*512 + lane*8 + j*2 + c  ->  W[(mt*16+(lane>>4)*4+j)*L + 32 + c]
constexpr int WP_FRAG = 36864;    // ushorts per hi/lo plane
constexpr int WP_TAILF = 36864;   // f32 tail count
// smem: CT f32 [64][145] bytes [0,37120) (aliases one-time mT staging, 16 KB)
//       so f32 [4][112]  bytes [37120, 38912)
constexpr int SMEM_BYTES = 64 * CTS * 4 + 4 * SOS * 4;  // 38912

__device__ __forceinline__ ushort_t f2bf(float v) {
    uint_t u = __float_as_uint(v);
    return (ushort_t)((u + 0x7fffu + ((u >> 16) & 1u)) >> 16);   // RTNE
}
__device__ __forceinline__ float bf2f(ushort_t h) {
    return __uint_as_float(((uint_t)h) << 16);
}

// DPP row_shr:N accumulate (pure VALU, no LDS-pipe traffic).
template <int CTRL>
__device__ __forceinline__ float dpp_shr_add(float v) {
    int x = __builtin_amdgcn_update_dpp(0, __float_as_int(v), CTRL, 0xF, 0xF, true);
    return v + __int_as_float(x);
}

// Pre-kernel: W -> {hi,lo bf16 frags for l=0..31} + {exact f32 tail l=32,33}.
__global__ void wprep_kernel(const float* __restrict__ W, ushort_t* __restrict__ wp) {
    int x = blockIdx.x * 256 + threadIdx.x;
    if (x < 2 * WP_FRAG) {
        int sp = x / WP_FRAG;
        int r  = x % WP_FRAG;
        int i  = r & 7;
        int ln = (r >> 3) & 63;
        int mt = r >> 9;
        int ok = mt * 16 + (ln & 15);
        int l  = (ln >> 4) * 8 + i;               // 0..31, always < L
        float v = W[ok * L + l];
        ushort_t hi = f2bf(v);
        wp[x] = sp ? f2bf(v - bf2f(hi)) : hi;
    } else if (x < 2 * WP_FRAG + WP_TAILF) {
        int y  = x - 2 * WP_FRAG;
        int c  = y & 1;
        int j  = (y >> 1) & 3;
        int ln = (y >> 3) & 63;
        int mt = y >> 9;
        int row = mt * 16 + (ln >> 4) * 4 + j;
        ((float*)(wp + 2 * WP_FRAG))[y] = W[row * L + 32 + c];
    }
}

// Grid (bs, 2). Each block: 4 chunks of 16 o-channels.
// Stage 1: 12 MFMAs/tile (3-product hi/lo, K=0..31) + exact f32 VALU K-tail
// (l=32,33) -> relu -> CT. BAR1. Stage 2: f32 VALU + DPP row-reduce -> so.
// BAR2. Epilogue. (256,4): live state ~121 regs fits 128-reg cap spill-free
// (B-frags halved vs r7 by moving the K-tail out of MFMA).
__global__ __launch_bounds__(256, 4) void iconv_mfma(
    const float* __restrict__ pep,
    const float* __restrict__ mhc,
    const ushort_t* __restrict__ wp,
    const float* __restrict__ bias,
    float* __restrict__ out)
{
    __shared__ __align__(16) char smem[SMEM_BYTES];
    const int n    = blockIdx.x;
    const int c0   = blockIdx.y * NCHB;             // chunk offset for this block
    const int tid  = threadIdx.x;
    const int lane = tid & 63;
    const int w    = tid >> 6;

    // peptide column (lane = d)
    float p[PEP];
    {
        const float* pp = pep + (size_t)n * PEP * D + lane;
        #pragma unroll
        for (int j = 0; j < PEP; ++j) p[j] = pp[j * D];
    }

    // m rows 32,33 in exact f32, per-nt (d = (lane&15)+16*nt)
    float m32v[4], m33v[4];
    {
        const float* mb = mhc + (size_t)n * L * D;
        #pragma unroll
        for (int nt = 0; nt < 4; ++nt) {
            int d = (lane & 15) + 16 * nt;
            m32v[nt] = mb[32 * D + d];
            m33v[nt] = mb[33 * D + d];
        }
    }

    // Stage m^T (l=0..31 only) into LDS as hi/lo bf16, XOR-swizzled (one-time)
    {
        const float* mp = mhc + (size_t)n * L * D + lane;
        #pragma unroll
        for (int j = 0; j < 8; ++j) {
            int l = w + 4 * j;                      // 0..31
            float v = mp[l * D];
            ushort_t hi = f2bf(v);
            ushort_t lo = f2bf(v - bf2f(hi));
            int byte = (lane * 128 + l * 2) ^ ((lane & 7) << 4);
            *(ushort_t*)(smem + byte)        = hi;
            *(ushort_t*)(smem + 8192 + byte) = lo;
        }
    }
    __syncthreads();

    // B-fragments: [nt][hi/lo], k-half 0 only (32 VGPRs)
    bf16x8 bf[4][2];
    #pragma unroll
    for (int nt = 0; nt < 4; ++nt) {
        int d = (lane & 15) + 16 * nt;
        int l0 = (lane >> 4) * 8;
        int byte = (d * 128 + l0 * 2) ^ ((d & 7) << 4);
        bf[nt][0] = *(const bf16x8*)(smem + byte);
        bf[nt][1] = *(const bf16x8*)(smem + 8192 + byte);
    }
    __syncthreads();   // mT dead; CT may overwrite

    float* CT  = (float*)smem;                      // [d][CTS]
    float* so  = (float*)(smem + 64 * CTS * 4);     // [4][SOS]
    float* CTl = CT + lane * CTS;                   // stage-2 row base
    const float* wtail = (const float*)(wp + 2 * WP_FRAG);

    // one M-tile: A-frags (hi/lo), 12 MFMAs, exact f32 K-tail, relu -> CT
    auto do_tile = [&](int cg, int mtl) {
        int mtG = cg * MT_CH + mtl;
        const ushort_t* base = wp + mtG * 512 + lane * 8;
        bf16x8 ah = *(const bf16x8*)(base);
        bf16x8 al = *(const bf16x8*)(base + WP_FRAG);
        const float4* tb = (const float4*)(wtail + (size_t)(mtG * 64 + lane) * 8);
        float4 ft0 = tb[0];                         // (j0w32,j0w33,j1w32,j1w33)
        float4 ft1 = tb[1];                         // (j2w32,j2w33,j3w32,j3w33)

        f32x4 acc[4];
        #pragma unroll
        for (int nt = 0; nt < 4; ++nt) acc[nt] = (f32x4){0.f, 0.f, 0.f, 0.f};
        #pragma unroll
        for (int nt = 0; nt < 4; ++nt) {
            acc[nt] = __builtin_amdgcn_mfma_f32_16x16x32_bf16(ah, bf[nt][0], acc[nt], 0, 0, 0);
            acc[nt] = __builtin_amdgcn_mfma_f32_16x16x32_bf16(ah, bf[nt][1], acc[nt], 0, 0, 0);
            acc[nt] = __builtin_amdgcn_mfma_f32_16x16x32_bf16(al, bf[nt][0], acc[nt], 0, 0, 0);
        }
        // exact K-tail: rows r0+j, cols d: += W[row][32]*m32[d] + W[row][33]*m33[d]
        #pragma unroll
        for (int nt = 0; nt < 4; ++nt) {
            acc[nt][0] = fmaf(ft0.x, m32v[nt], fmaf(ft0.y, m33v[nt], acc[nt][0]));
            acc[nt][1] = fmaf(ft0.z, m32v[nt], fmaf(ft0.w, m33v[nt], acc[nt][1]));
            acc[nt][2] = fmaf(ft1.x, m32v[nt], fmaf(ft1.y, m33v[nt], acc[nt][2]));
            acc[nt][3] = fmaf(ft1.z, m32v[nt], fmaf(ft1.w, m33v[nt], acc[nt][3]));
        }

        int r0 = mtl * 16 + (lane >> 4) * 4;
        #pragma unroll
        for (int nt = 0; nt < 4; ++nt) {
            int d = (lane & 15) + 16 * nt;
            float* dst = CT + d * CTS + r0;
            dst[0] = fmaxf(acc[nt][0], 0.f);
            dst[1] = fmaxf(acc[nt][1], 0.f);
            dst[2] = fmaxf(acc[nt][2], 0.f);
            dst[3] = fmaxf(acc[nt][3], 0.f);
        }
    };

    for (int c = 0; c < NCHB; ++c) {
        const int cg = c0 + c;                      // global chunk id

        // ---------- stage 1: tiles {w, w+4} + rotated 9th tile ----------
        do_tile(cg, w);
        do_tile(cg, w + 4);
        if (w == (cg & 3)) do_tile(cg, 8);          // balanced across chunks
        __syncthreads();   // BAR1: CT complete

        // ---------- stage 2: f32 VALU, lane = d; two oi-halves ----------
        #pragma unroll
        for (int h = 0; h < 2; ++h) {
            float a2[2][TO];
            #pragma unroll
            for (int oi = 0; oi < 2; ++oi)
                #pragma unroll
                for (int t = 0; t < TO; ++t) a2[oi][t] = 0.f;

            #pragma unroll
            for (int oi = 0; oi < 2; ++oi) {
                const float* row = CTl + (w * 4 + h * 2 + oi) * KS;  // conflict-free
                #pragma unroll
                for (int k = 0; k < KS; ++k) {
                    float kk = row[k];
                    #pragma unroll
                    for (int t = 0; t < TO; ++t) a2[oi][t] = fmaf(kk, p[t + k], a2[oi][t]);
                }
            }

            #pragma unroll
            for (int oi = 0; oi < 2; ++oi) {
                #pragma unroll
                for (int t = 0; t < TO; ++t) {
                    float a = a2[oi][t];
                    a = dpp_shr_add<0x111>(a);   // row_shr:1
                    a = dpp_shr_add<0x112>(a);   // row_shr:2
                    a = dpp_shr_add<0x114>(a);   // row_shr:4
                    a = dpp_shr_add<0x118>(a);   // row_shr:8
                    if ((lane & 15) == 15)
                        so[(lane >> 4) * SOS + (w * 4 + h * 2 + oi) * TO + t] = a;
                }
            }
        }
        __syncthreads();   // BAR2: so complete; CT reads complete

        // epilogue: this chunk's 112 outputs
        if (tid < SOS) {
            int o = cg * CHO + tid / TO;
            float v = (so[tid] + so[SOS + tid]) +
                      (so[2 * SOS + tid] + so[3 * SOS + tid]);
            out[(size_t)n * OC * TO + cg * SOS + tid] = v + bias[o];
        }
        // no barrier needed: next stage-1 writes CT only; next so-write is
        // after next BAR1 which orders it against these so-reads.
    }
}

// ---------------- fallback (f32 VALU, known-good) ----------------
__global__ __launch_bounds__(256, 4) void iconv_f32(
    const float* __restrict__ pep, const float* __restrict__ mhc,
    const float* __restrict__ wsrc, const float* __restrict__ bias,
    float* __restrict__ out)
{
    __shared__ float so[4 * 900];
    const int n = blockIdx.x, tid = threadIdx.x, lane = tid & 63;
    const int w = __builtin_amdgcn_readfirstlane(tid >> 6);
    float m[L];
    { const float* mp = mhc + (size_t)n * L * D + lane;
      #pragma unroll
      for (int l = 0; l < L; ++l) m[l] = mp[l * D]; }
    float p[PEP];
    { const float* pp = pep + (size_t)n * PEP * D + lane;
      #pragma unroll
      for (int j = 0; j < PEP; ++j) p[j] = pp[j * D]; }
    for (int oo = 0; oo < OC / 4; ++oo) {
        const int o = w * (OC / 4) + oo;
        float acc[TO];
        #pragma unroll
        for (int t = 0; t < TO; ++t) acc[t] = 0.f;
        #pragma unroll
        for (int k = 0; k < KS; ++k) {
            const float2* wrow = reinterpret_cast<const float2*>(wsrc + (size_t)o * KS * L);
            float wr[L];
            #pragma unroll
            for (int q = 0; q < L / 2; ++q) {
                float2 v = wrow[k * (L / 2) + q];
                wr[q * 2] = v.x; wr[q * 2 + 1] = v.y;
            }
            float k0 = 0.f, k1 = 0.f, k2 = 0.f, k3 = 0.f;
            #pragma unroll
            for (int l = 0; l < 32; l += 4) {
                k0 = fmaf(m[l], wr[l], k0);   k1 = fmaf(m[l + 1], wr[l + 1], k1);
                k2 = fmaf(m[l + 2], wr[l + 2], k2); k3 = fmaf(m[l + 3], wr[l + 3], k3);
            }
            k0 = fmaf(m[32], wr[32], k0); k1 = fmaf(m[33], wr[33], k1);
            float kk = fmaxf((k0 + k2) + (k1 + k3), 0.f);
            #pragma unroll
            for (int t = 0; t < TO; ++t) acc[t] = fmaf(p[t + k], kk, acc[t]);
        }
        #pragma unroll
        for (int t = 0; t < TO; ++t) {
            float a = acc[t];
            a += __shfl_xor(a, 1, 64); a += __shfl_xor(a, 2, 64);
            a += __shfl_xor(a, 4, 64); a += __shfl_xor(a, 8, 64);
            if ((lane & 15) == 0) so[(lane >> 4) * 900 + o * TO + t] = a;
        }
    }
    __syncthreads();
    float* on = out + (size_t)n * OC * TO;
    for (int i = tid; i < OC * TO; i += 256) {
        int o = i / TO;
        on[i] = (so[i] + so[900 + i]) + (so[1800 + i] + so[2700 + i]) + bias[o];
    }
}

extern "C" void kernel_launch(void* const* d_in, const int* in_sizes, int n_in,
                              void* d_out, int out_size, void* d_ws, size_t ws_size,
                              hipStream_t stream) {
    const float* pep  = (const float*)d_in[0];
    const float* mhc  = (const float*)d_in[1];
    const float* W    = (const float*)d_in[2];
    const float* bias = (const float*)d_in[3];
    float* out        = (float*)d_out;
    const int bs = in_sizes[0] / (PEP * D);

    const size_t need = 2 * WP_FRAG * sizeof(ushort_t) + WP_TAILF * sizeof(float); // 294912
    if (d_ws != nullptr && ws_size >= need) {
        ushort_t* wpx = (ushort_t*)d_ws;
        const int tot = 2 * WP_FRAG + WP_TAILF;     // 110592 threads
        wprep_kernel<<<(tot + 255) / 256, 256, 0, stream>>>(W, wpx);
        iconv_mfma<<<dim3(bs, 2), 256, 0, stream>>>(pep, mhc, wpx, bias, out);
    } else {
        iconv_f32<<<bs, 256, 0, stream>>>(pep, mhc, W, bias, out);
    }
}